// Round 4
// baseline (98.855 us; speedup 1.0000x reference)
//
#include <hip/hip_runtime.h>
#include <math.h>

#define D 128

// out_e = tanh( u . f[src_e] + v . f[dst_e] + c )
//   u = W1^T (wa + wb),  v = W1^T (wb - wa),  c = 2*wb.b1 + b2
//   where wa = W2[0,:128], wb = W2[0,128:]
// Main path: st[n] = (u.f[n] + c, v.f[n]);  out_e = tanh(st[src].x + st[dst].y)

// Fused prep + node pass. Persistent blocks; each block computes u,v,c into LDS
// (redundantly, ~64KB W1 from L2 per block), then grid-strides the node rows.
__global__ void __launch_bounds__(256) node_fused_kernel(
        const float* __restrict__ W1, const float* __restrict__ b1,
        const float* __restrict__ W2, const float* __restrict__ b2,
        const float* __restrict__ feat, float2* __restrict__ st, int N) {
    __shared__ float uv[2 * D + 2];   // interleaved pairs (u[d],v[d]); uv[2D]=c
    __shared__ float red[2 * D];      // chunk-0 partials
    __shared__ float csc[D];          // per-d contributions to c
    int tid = threadIdx.x;            // 0..255
    int d = tid & (D - 1);
    int ch = tid >> 7;                // 0 or 1: o-range half
    float u = 0.f, v = 0.f;
    int o0 = ch * 64;
    #pragma unroll 16
    for (int k = 0; k < 64; ++k) {
        int o = o0 + k;
        float wa = W2[o];
        float wb = W2[D + o];
        float w1 = W1[o * D + d];     // coalesced across d, L2-resident
        u += (wa + wb) * w1;
        v += (wb - wa) * w1;
    }
    if (ch == 0) { red[d] = u; red[D + d] = v; csc[d] = 2.f * W2[D + d] * b1[d]; }
    __syncthreads();
    if (ch == 1) {
        uv[2 * d]     = red[d] + u;
        uv[2 * d + 1] = red[D + d] + v;
    }
    if (tid == 0) {
        float cc = b2[0];
        #pragma unroll 16
        for (int o = 0; o < D; ++o) cc += csc[o];
        uv[2 * D] = cc;
    }
    __syncthreads();
    float c = uv[2 * D];

    // Node pass: 2 nodes per wave, float4 per lane, grid-stride.
    int lane = tid & 63;
    int half = lane >> 5;
    int l = lane & 31;
    int waveInBlock = tid >> 6;       // 0..3
    int stride = gridDim.x * 8;       // nodes per grid iteration
    float4 a = ((const float4*)uv)[2 * l];      // u[4l],v[4l],u[4l+1],v[4l+1]
    float4 b = ((const float4*)uv)[2 * l + 1];  // u[4l+2],v[4l+2],u[4l+3],v[4l+3]
    for (int node = blockIdx.x * 8 + waveInBlock * 2 + half; node < N; node += stride) {
        float4 f = ((const float4*)(feat + (size_t)node * D))[l];
        float s = f.x * a.x + f.y * a.z + f.z * b.x + f.w * b.z;
        float t = f.x * a.y + f.y * a.w + f.z * b.y + f.w * b.w;
        #pragma unroll
        for (int off = 16; off; off >>= 1) {   // xor<32 stays within half-wave
            s += __shfl_xor(s, off, 64);
            t += __shfl_xor(t, off, 64);
        }
        if (l == 0) st[node] = make_float2(s + c, t);
    }
}

// Edge pass: pure gather + tanh, no weight state needed.
__global__ void edge_kernel(const int* __restrict__ src, const int* __restrict__ dst,
                            const float2* __restrict__ st, float* __restrict__ out, int E) {
    int i = blockIdx.x * blockDim.x + threadIdx.x;
    int e0 = i * 4;
    if (e0 >= E) return;
    if (e0 + 3 < E) {
        int4 si = ((const int4*)src)[i];
        int4 di = ((const int4*)dst)[i];
        float2 a0 = st[si.x], a1 = st[si.y], a2 = st[si.z], a3 = st[si.w];
        float2 b0 = st[di.x], b1v = st[di.y], b2v = st[di.z], b3 = st[di.w];
        float4 r;
        r.x = tanhf(a0.x + b0.y);
        r.y = tanhf(a1.x + b1v.y);
        r.z = tanhf(a2.x + b2v.y);
        r.w = tanhf(a3.x + b3.y);
        ((float4*)out)[i] = r;
    } else {
        for (int e = e0; e < E; ++e)
            out[e] = tanhf(st[src[e]].x + st[dst[e]].y);
    }
}

// ---- Fallback path (workspace too small for st): prep to global + fused edge ----
__global__ void prep_kernel(const float* __restrict__ W1, const float* __restrict__ b1,
                            const float* __restrict__ W2, const float* __restrict__ b2,
                            float* __restrict__ uvc) {
    __shared__ float su[4 * D];
    __shared__ float sv[4 * D];
    __shared__ float sc[D];
    int tid = threadIdx.x;          // 0..511
    int d = tid & (D - 1);
    int ch = tid >> 7;              // 0..3
    float u = 0.f, v = 0.f;
    int o0 = ch * 32;
    #pragma unroll 8
    for (int k = 0; k < 32; ++k) {
        int o = o0 + k;
        float wa = W2[o];
        float wb = W2[D + o];
        float w1 = W1[o * D + d];
        u += (wa + wb) * w1;
        v += (wb - wa) * w1;
    }
    su[ch * D + d] = u;
    sv[ch * D + d] = v;
    if (ch == 0) sc[d] = 2.f * W2[D + d] * b1[d];
    __syncthreads();
    if (tid < D) {
        uvc[2 * d]     = su[d] + su[D + d] + su[2 * D + d] + su[3 * D + d];
        uvc[2 * d + 1] = sv[d] + sv[D + d] + sv[2 * D + d] + sv[3 * D + d];
    } else if (tid == D) {
        float cc = b2[0];
        for (int o = 0; o < D; ++o) cc += sc[o];
        uvc[2 * D] = cc;
    }
}

__global__ void fused_edge_kernel(const float* __restrict__ feat,
                                  const int* __restrict__ src, const int* __restrict__ dst,
                                  const float* __restrict__ uvc, float* __restrict__ out, int E) {
    int wave = (int)((blockIdx.x * blockDim.x + threadIdx.x) >> 6);
    int lane = threadIdx.x & 63;
    if (wave >= E) return;
    int sn = src[wave], dn = dst[wave];
    float2 fs = ((const float2*)(feat + (size_t)sn * D))[lane];
    float2 fd = ((const float2*)(feat + (size_t)dn * D))[lane];
    float2 p = ((const float2*)uvc)[2 * lane];
    float2 q = ((const float2*)uvc)[2 * lane + 1];
    float acc = fs.x * p.x + fs.y * q.x + fd.x * p.y + fd.y * q.y;
    #pragma unroll
    for (int off = 32; off; off >>= 1) acc += __shfl_xor(acc, off, 64);
    if (lane == 0) out[wave] = tanhf(acc + uvc[2 * D]);
}

extern "C" void kernel_launch(void* const* d_in, const int* in_sizes, int n_in,
                              void* d_out, int out_size, void* d_ws, size_t ws_size,
                              hipStream_t stream) {
    const float* feat = (const float*)d_in[0];
    const int*   src  = (const int*)d_in[1];
    const int*   dst  = (const int*)d_in[2];
    const float* W1   = (const float*)d_in[3];
    const float* b1   = (const float*)d_in[4];
    const float* W2   = (const float*)d_in[5];
    const float* b2   = (const float*)d_in[6];
    float* out = (float*)d_out;

    int N = in_sizes[0] / D;
    int E = in_sizes[1];

    size_t needed = 2 * (size_t)N * sizeof(float);

    if (ws_size >= needed) {
        float2* st = (float2*)d_ws;
        int nblocks = 512;
        if (nblocks > (N + 7) / 8) nblocks = (N + 7) / 8;
        node_fused_kernel<<<nblocks, 256, 0, stream>>>(W1, b1, W2, b2, feat, st, N);
        int nthreads = (E + 3) / 4;
        edge_kernel<<<(nthreads + 255) / 256, 256, 0, stream>>>(src, dst, st, out, E);
    } else {
        float* uvc = (float*)d_ws;  // needs 257 floats
        prep_kernel<<<1, 512, 0, stream>>>(W1, b1, W2, b2, uvc);
        int nblocks = (E + 3) / 4;  // wave per edge
        fused_edge_kernel<<<nblocks, 256, 0, stream>>>(feat, src, dst, uvc, out, E);
    }
}

// Round 5
// 96.308 us; speedup vs baseline: 1.0264x; 1.0264x over previous
//
#include <hip/hip_runtime.h>
#include <math.h>

#define D 128

// out_e = tanh( u . f[src_e] + v . f[dst_e] + c )
//   u = W1^T (wa + wb),  v = W1^T (wb - wa),  c = 2*wb.b1 + b2
//   where wa = W2[0,:128], wb = W2[0,128:]
// st[n] = (u.f[n] + c, v.f[n]);  out_e = tanh(st[src].x + st[dst].y)

// Phase 0: fold weights. 1024 threads: d = tid&127, o-chunk = tid>>7 (8 chunks
// of 16) -> 16 serial iterations per thread, LDS reduce.
__global__ void prep_kernel(const float* __restrict__ W1, const float* __restrict__ b1,
                            const float* __restrict__ W2, const float* __restrict__ b2,
                            float* __restrict__ uvc) {
    __shared__ float su[8 * D];
    __shared__ float sv[8 * D];
    __shared__ float sc[D];
    int tid = threadIdx.x;          // 0..1023
    int d = tid & (D - 1);
    int ch = tid >> 7;              // 0..7
    float u = 0.f, v = 0.f;
    int o0 = ch * 16;
    #pragma unroll
    for (int k = 0; k < 16; ++k) {
        int o = o0 + k;
        float wa = W2[o];
        float wb = W2[D + o];
        float w1 = W1[o * D + d];   // coalesced across d
        u += (wa + wb) * w1;
        v += (wb - wa) * w1;
    }
    su[ch * D + d] = u;
    sv[ch * D + d] = v;
    if (ch == 0) sc[d] = 2.f * W2[D + d] * b1[d];
    __syncthreads();
    if (tid < D) {
        float uu = 0.f, vv = 0.f;
        #pragma unroll
        for (int j = 0; j < 8; ++j) { uu += su[j * D + d]; vv += sv[j * D + d]; }
        uvc[2 * d]     = uu;        // interleaved (u[d], v[d])
        uvc[2 * d + 1] = vv;
    } else if (tid == D) {
        float cc = b2[0];
        #pragma unroll
        for (int o = 0; o < D; ++o) cc += sc[o];
        uvc[2 * D] = cc;
    }
}

// Phase 1: st[n] = (u.f[n] + c, v.f[n]). Two nodes per wave, float4 per lane.
__global__ void node_kernel(const float* __restrict__ feat, const float* __restrict__ uvc,
                            float2* __restrict__ st, int N) {
    int wave = (int)((blockIdx.x * blockDim.x + threadIdx.x) >> 6);
    int lane = threadIdx.x & 63;
    int half = lane >> 5;           // 0 or 1
    int l = lane & 31;              // lane within half-wave
    int node = wave * 2 + half;
    if (node >= N) return;
    float4 f = ((const float4*)(feat + (size_t)node * D))[l];
    float4 a = ((const float4*)uvc)[2 * l];     // u[4l],v[4l],u[4l+1],v[4l+1]
    float4 b = ((const float4*)uvc)[2 * l + 1]; // u[4l+2],v[4l+2],u[4l+3],v[4l+3]
    float c = uvc[2 * D];
    float s = f.x * a.x + f.y * a.z + f.z * b.x + f.w * b.z;
    float t = f.x * a.y + f.y * a.w + f.z * b.y + f.w * b.w;
    #pragma unroll
    for (int off = 16; off; off >>= 1) {  // xor<32 stays within half-wave
        s += __shfl_xor(s, off, 64);
        t += __shfl_xor(t, off, 64);
    }
    if (l == 0) st[node] = make_float2(s + c, t);
}

// Phase 2: per-edge gather + tanh. 4 edges/thread; one 8B st load per endpoint.
__global__ void edge_kernel(const int* __restrict__ src, const int* __restrict__ dst,
                            const float2* __restrict__ st, float* __restrict__ out, int E) {
    int i = blockIdx.x * blockDim.x + threadIdx.x;
    int e0 = i * 4;
    if (e0 >= E) return;
    if (e0 + 3 < E) {
        int4 si = ((const int4*)src)[i];
        int4 di = ((const int4*)dst)[i];
        float2 a0 = st[si.x], a1 = st[si.y], a2 = st[si.z], a3 = st[si.w];
        float2 b0 = st[di.x], b1v = st[di.y], b2v = st[di.z], b3 = st[di.w];
        float4 r;
        r.x = tanhf(a0.x + b0.y);
        r.y = tanhf(a1.x + b1v.y);
        r.z = tanhf(a2.x + b2v.y);
        r.w = tanhf(a3.x + b3.y);
        ((float4*)out)[i] = r;
    } else {
        for (int e = e0; e < E; ++e)
            out[e] = tanhf(st[src[e]].x + st[dst[e]].y);
    }
}

// ---- Fallback path (workspace too small for st): fused per-edge dot ----
__global__ void fused_edge_kernel(const float* __restrict__ feat,
                                  const int* __restrict__ src, const int* __restrict__ dst,
                                  const float* __restrict__ uvc, float* __restrict__ out, int E) {
    int wave = (int)((blockIdx.x * blockDim.x + threadIdx.x) >> 6);
    int lane = threadIdx.x & 63;
    if (wave >= E) return;
    int sn = src[wave], dn = dst[wave];
    float2 fs = ((const float2*)(feat + (size_t)sn * D))[lane];
    float2 fd = ((const float2*)(feat + (size_t)dn * D))[lane];
    float2 p = ((const float2*)uvc)[2 * lane];
    float2 q = ((const float2*)uvc)[2 * lane + 1];
    float acc = fs.x * p.x + fs.y * q.x + fd.x * p.y + fd.y * q.y;
    #pragma unroll
    for (int off = 32; off; off >>= 1) acc += __shfl_xor(acc, off, 64);
    if (lane == 0) out[wave] = tanhf(acc + uvc[2 * D]);
}

extern "C" void kernel_launch(void* const* d_in, const int* in_sizes, int n_in,
                              void* d_out, int out_size, void* d_ws, size_t ws_size,
                              hipStream_t stream) {
    const float* feat = (const float*)d_in[0];
    const int*   src  = (const int*)d_in[1];
    const int*   dst  = (const int*)d_in[2];
    const float* W1   = (const float*)d_in[3];
    const float* b1   = (const float*)d_in[4];
    const float* W2   = (const float*)d_in[5];
    const float* b2   = (const float*)d_in[6];
    float* out = (float*)d_out;

    int N = in_sizes[0] / D;
    int E = in_sizes[1];

    float* uvc = (float*)d_ws;              // 257 floats used, pad to 512
    float2* st = (float2*)((float*)d_ws + 512);
    size_t needed = (512 + 2 * (size_t)N) * sizeof(float);

    prep_kernel<<<1, 1024, 0, stream>>>(W1, b1, W2, b2, uvc);

    if (ws_size >= needed) {
        // node pass: 2 nodes/wave, 4 waves per 256-thread block -> 8 nodes/block
        int nblocks = (N + 7) / 8;
        node_kernel<<<nblocks, 256, 0, stream>>>(feat, uvc, st, N);
        // edge pass: 4 edges per thread
        int nthreads = (E + 3) / 4;
        edge_kernel<<<(nthreads + 255) / 256, 256, 0, stream>>>(src, dst, st, out, E);
    } else {
        int nblocks = (E + 3) / 4;          // wave per edge
        fused_edge_kernel<<<nblocks, 256, 0, stream>>>(feat, src, dst, uvc, out, E);
    }
}